// Round 1
// baseline (1430.637 us; speedup 1.0000x reference)
//
#include <hip/hip_runtime.h>

// Problem constants: B=16, 3*NF=12 in-ch, 128x128 images, conv1->64ch, pool->64x64,
// conv2->128ch, NOBJ=32, out (16,32,128) f32.

namespace {

__device__ __forceinline__ float ldz(const float* __restrict__ p, int h, int w,
                                     int H, int W, int ld) {
  return (h >= 0 && h < H && w >= 0 && w < W) ? p[h * ld + w] : 0.f;
}

// ---------------- k0: rois[:,:,::2,::2] -> per-position 32-bit object mask ----
// rmask[b*4096 + h*64 + w] bit o = rois[b,o,2h,2w] != 0.
// Detects on-device whether rois elements are 4-byte (int32/float32) or 1-byte
// (bool) — scan of first 256 words is deterministic for fixed inputs.
__global__ __launch_bounds__(256) void k0_rmask(const unsigned* __restrict__ rois,
                                                unsigned* __restrict__ rmask) {
  const int lane = threadIdx.x & 63;
  unsigned ok = 1u;
#pragma unroll
  for (int i = 0; i < 4; ++i) {
    unsigned v = rois[lane * 4 + i];
    ok &= ((v <= 1u) || (v == 0x3f800000u)) ? 1u : 0u;
  }
  const bool isWord = (__all((int)ok) != 0);  // 4-byte elements
  const unsigned char* roisB = (const unsigned char*)rois;

  const int pos = blockIdx.x * 256 + threadIdx.x;  // 0 .. 65535
  const int b = pos >> 12;
  const int p = pos & 4095;
  const int h = (p >> 6) << 1;  // 2*h
  const int w = (p & 63) << 1;  // 2*w
  const size_t base = (size_t)b * 32 * 16384 + (size_t)h * 128 + (size_t)w;
  unsigned m = 0;
#pragma unroll
  for (int o = 0; o < 32; ++o) {
    const size_t idx = base + (size_t)o * 16384;
    unsigned bit = isWord ? (unsigned)(rois[idx] != 0u) : (unsigned)(roisB[idx] != 0);
    m |= bit << o;
  }
  rmask[pos] = m;
}

// ---------------- k1: conv1 (12->64, 3x3 SAME) + bias + relu + maxpool 2x2 ----
// grid (4 rowblk, 64 co, 16 b); 256 thr; each thread -> 2x2 pooled outputs
// (4x4 conv region, 6x6 input patch per input channel).
__global__ __launch_bounds__(256) void k1_conv1_pool(const float* __restrict__ img,
                                                     const float* __restrict__ w1,
                                                     const float* __restrict__ b1,
                                                     float* __restrict__ pooled) {
  __shared__ float sw[108];  // w1[co] : 12*3*3
  const int rowblk = blockIdx.x, co = blockIdx.y, b = blockIdx.z;
  const int t = threadIdx.x;
  if (t < 108) sw[t] = w1[co * 108 + t];
  __syncthreads();

  const int ph0 = rowblk * 16 + (t >> 5) * 2;  // pooled row
  const int pw0 = (t & 31) * 2;                // pooled col
  const int h0 = ph0 * 2, w0 = pw0 * 2;        // conv-output coords

  float acc[4][4];
#pragma unroll
  for (int i = 0; i < 4; ++i) {
#pragma unroll
    for (int j = 0; j < 4; ++j) acc[i][j] = 0.f;
  }

  for (int ci = 0; ci < 12; ++ci) {
    const float* plane = img + (size_t)(b * 12 + ci) * 16384;
    float wt[9];
#pragma unroll
    for (int k = 0; k < 9; ++k) wt[k] = sw[ci * 9 + k];
    float p[6][6];
#pragma unroll
    for (int r = 0; r < 6; ++r) {
#pragma unroll
      for (int c = 0; c < 6; ++c) {
        p[r][c] = ldz(plane, h0 - 1 + r, w0 - 1 + c, 128, 128, 128);
      }
    }
#pragma unroll
    for (int di = 0; di < 4; ++di) {
#pragma unroll
      for (int dj = 0; dj < 4; ++dj) {
        float s = acc[di][dj];
#pragma unroll
        for (int kh = 0; kh < 3; ++kh) {
#pragma unroll
          for (int kw = 0; kw < 3; ++kw) {
            s = fmaf(p[di + kh][dj + kw], wt[kh * 3 + kw], s);
          }
        }
        acc[di][dj] = s;
      }
    }
  }

  const float bias = b1[co];
  float* outp = pooled + (size_t)(b * 64 + co) * 4096;
#pragma unroll
  for (int i = 0; i < 2; ++i) {
#pragma unroll
    for (int j = 0; j < 2; ++j) {
      float r00 = fmaxf(acc[2 * i][2 * j] + bias, 0.f);
      float r01 = fmaxf(acc[2 * i][2 * j + 1] + bias, 0.f);
      float r10 = fmaxf(acc[2 * i + 1][2 * j] + bias, 0.f);
      float r11 = fmaxf(acc[2 * i + 1][2 * j + 1] + bias, 0.f);
      outp[(ph0 + i) * 64 + (pw0 + j)] = fmaxf(fmaxf(r00, r01), fmaxf(r10, r11));
    }
  }
}

// ---------------- k2: conv2 (64->128, 3x3 SAME) + bias + relu + pos-embed ----
// grid (128 co, 16 b); 256 thr; each thread -> 4x4 outputs of the 64x64 plane.
// pe(h,w,co) = gy*(W0-W2) + gx*(W1-W3) + W2 + W3 + db[co], g = idx/63.
__global__ __launch_bounds__(256) void k2_conv2_pe(const float* __restrict__ pooled,
                                                   const float* __restrict__ w2,
                                                   const float* __restrict__ b2,
                                                   const float* __restrict__ dw,
                                                   const float* __restrict__ db,
                                                   float* __restrict__ x2) {
  __shared__ float sw[576];  // w2[co] : 64*3*3
  const int co = blockIdx.x, b = blockIdx.y;
  const int t = threadIdx.x;
  for (int i = t; i < 576; i += 256) sw[i] = w2[co * 576 + i];
  __syncthreads();

  const int h0 = (t >> 4) * 4;
  const int w0 = (t & 15) * 4;

  float acc[4][4];
#pragma unroll
  for (int i = 0; i < 4; ++i) {
#pragma unroll
    for (int j = 0; j < 4; ++j) acc[i][j] = 0.f;
  }

  for (int ci = 0; ci < 64; ++ci) {
    const float* plane = pooled + (size_t)(b * 64 + ci) * 4096;
    float wt[9];
#pragma unroll
    for (int k = 0; k < 9; ++k) wt[k] = sw[ci * 9 + k];
    float p[6][6];
#pragma unroll
    for (int r = 0; r < 6; ++r) {
#pragma unroll
      for (int c = 0; c < 6; ++c) {
        p[r][c] = ldz(plane, h0 - 1 + r, w0 - 1 + c, 64, 64, 64);
      }
    }
#pragma unroll
    for (int di = 0; di < 4; ++di) {
#pragma unroll
      for (int dj = 0; dj < 4; ++dj) {
        float s = acc[di][dj];
#pragma unroll
        for (int kh = 0; kh < 3; ++kh) {
#pragma unroll
          for (int kw = 0; kw < 3; ++kw) {
            s = fmaf(p[di + kh][dj + kw], wt[kh * 3 + kw], s);
          }
        }
        acc[di][dj] = s;
      }
    }
  }

  const float bias = b2[co];
  const float W0 = dw[co * 4 + 0], W1 = dw[co * 4 + 1];
  const float W2 = dw[co * 4 + 2], W3 = dw[co * 4 + 3];
  const float s02 = W0 - W2, s13 = W1 - W3;
  const float c23 = W2 + W3 + db[co];
  const float inv63 = 1.f / 63.f;

  float* outp = x2 + (size_t)(b * 128 + co) * 4096;
#pragma unroll
  for (int di = 0; di < 4; ++di) {
#pragma unroll
    for (int dj = 0; dj < 4; ++dj) {
      const int h = h0 + di, w = w0 + dj;
      const float pe = (float)h * inv63 * s02 + (float)w * inv63 * s13 + c23;
      outp[h * 64 + w] = fmaxf(acc[di][dj] + bias, 0.f) + pe;
    }
  }
}

// ---------------- k3: out[b,o,c] = max over pos of x2[b,c,pos] * r[b,o,pos] ---
// grid (128 c, 16 b); 256 thr scan the 4096-position plane once (coalesced);
// 32 running maxes per thread via bitmask; shuffle + LDS reduce.
__global__ __launch_bounds__(256) void k3_roi(const float* __restrict__ x2,
                                              const unsigned* __restrict__ rmask,
                                              float* __restrict__ out) {
  __shared__ float red[4][32];
  const int c = blockIdx.x, b = blockIdx.y;
  const int t = threadIdx.x;
  const float* plane = x2 + (size_t)(b * 128 + c) * 4096;
  const unsigned* mb = rmask + b * 4096;

  float m[32];
#pragma unroll
  for (int o = 0; o < 32; ++o) m[o] = -3.4e38f;

  for (int k = 0; k < 16; ++k) {
    const int pos = k * 256 + t;
    const float xv = plane[pos];
    const unsigned mk = mb[pos];
#pragma unroll
    for (int o = 0; o < 32; ++o) {
      m[o] = fmaxf(m[o], ((mk >> o) & 1u) ? xv : 0.f);
    }
  }

#pragma unroll
  for (int o = 0; o < 32; ++o) {
#pragma unroll
    for (int s = 32; s >= 1; s >>= 1) {
      m[o] = fmaxf(m[o], __shfl_xor(m[o], s, 64));
    }
  }
  const int wave = t >> 6, lane = t & 63;
  if (lane == 0) {
#pragma unroll
    for (int o = 0; o < 32; ++o) red[wave][o] = m[o];
  }
  __syncthreads();
  if (t < 32) {
    float v = fmaxf(fmaxf(red[0][t], red[1][t]), fmaxf(red[2][t], red[3][t]));
    out[((size_t)b * 32 + t) * 128 + c] = v;
  }
}

}  // namespace

extern "C" void kernel_launch(void* const* d_in, const int* in_sizes, int n_in,
                              void* d_out, int out_size, void* d_ws, size_t ws_size,
                              hipStream_t stream) {
  const float* images = (const float*)d_in[0];
  const unsigned* rois = (const unsigned*)d_in[1];
  const float* w1 = (const float*)d_in[2];
  const float* b1 = (const float*)d_in[3];
  const float* w2 = (const float*)d_in[4];
  const float* b2 = (const float*)d_in[5];
  const float* dw = (const float*)d_in[6];
  const float* db = (const float*)d_in[7];
  float* out = (float*)d_out;

  char* ws = (char*)d_ws;
  unsigned* rmask = (unsigned*)(ws + 0);             // 16*4096*4   = 256 KB
  float* pooled = (float*)(ws + (1 << 18));          // 16*64*64*64 = 16 MB
  float* x2 = (float*)(ws + (1 << 18) + (1 << 24));  // 16*128*64*64 = 32 MB

  hipLaunchKernelGGL(k0_rmask, dim3(256), dim3(256), 0, stream, rois, rmask);
  hipLaunchKernelGGL(k1_conv1_pool, dim3(4, 64, 16), dim3(256), 0, stream,
                     images, w1, b1, pooled);
  hipLaunchKernelGGL(k2_conv2_pe, dim3(128, 16), dim3(256), 0, stream,
                     pooled, w2, b2, dw, db, x2);
  hipLaunchKernelGGL(k3_roi, dim3(128, 16), dim3(256), 0, stream, x2, rmask, out);
}

// Round 2
// 117.878 us; speedup vs baseline: 12.1366x; 12.1366x over previous
//
#include <hip/hip_runtime.h>

// B=16, 12 in-ch, 128x128 imgs; conv1->64ch +pool -> 64x64; conv2->128ch (+PE);
// roi max -> out (16,32,128) f32.
//
// Pipeline: k0 (roi bitmask) ; k0b (images -> bf16 [b][row][col][ci16] imgT) ;
// kw/kw1 (weights -> bf16 MFMA-fragment order) ; k1_mfma (conv1+relu+pool ->
// bf16 pooledT [b][ph][pw][co]) ; k2_mfma (conv2+relu+PE -> f32 x2) ; k3 (roi max).

typedef __attribute__((ext_vector_type(8))) short short8;   // MFMA bf16 A/B frag
typedef __attribute__((ext_vector_type(4))) float f32x4;    // MFMA C/D frag
typedef __attribute__((ext_vector_type(4))) unsigned short us4;
typedef unsigned short u16;

__device__ __forceinline__ u16 f2bf(float f) {  // RNE f32 -> bf16 bits
  unsigned u = __builtin_bit_cast(unsigned, f);
  return (u16)((u + 0x7fffu + ((u >> 16) & 1u)) >> 16);
}

namespace {

// ---------------- k0: rois[:,:,::2,::2] -> per-position 32-bit object mask ----
__global__ __launch_bounds__(256) void k0_rmask(const unsigned* __restrict__ rois,
                                                unsigned* __restrict__ rmask) {
  const int lane = threadIdx.x & 63;
  unsigned ok = 1u;
#pragma unroll
  for (int i = 0; i < 4; ++i) {
    unsigned v = rois[lane * 4 + i];
    ok &= ((v <= 1u) || (v == 0x3f800000u)) ? 1u : 0u;
  }
  const bool isWord = (__all((int)ok) != 0);  // 4-byte elements
  const unsigned char* roisB = (const unsigned char*)rois;

  const int pos = blockIdx.x * 256 + threadIdx.x;
  const int b = pos >> 12;
  const int p = pos & 4095;
  const int h = (p >> 6) << 1;
  const int w = (p & 63) << 1;
  const size_t base = (size_t)b * 32 * 16384 + (size_t)h * 128 + (size_t)w;
  unsigned m = 0;
#pragma unroll
  for (int o = 0; o < 32; ++o) {
    const size_t idx = base + (size_t)o * 16384;
    unsigned bit = isWord ? (unsigned)(rois[idx] != 0u) : (unsigned)(roisB[idx] != 0);
    m |= bit << o;
  }
  rmask[pos] = m;
}

// ---------------- k0b: images f32 [b][12][128][128] -> bf16 imgT [b][row][col][16] (ci pad->0)
__global__ __launch_bounds__(256) void k0b_imgT(const float* __restrict__ img,
                                                u16* __restrict__ imgT) {
  __shared__ alignas(16) u16 ST[2048];  // [col 0..127][cip 0..15]
  const int row = blockIdx.x, b = blockIdx.y;
  const int t = threadIdx.x;
#pragma unroll
  for (int i = 0; i < 2; ++i) {  // zero pads cip 12..15
    const int e = i * 256 + t;   // 0..511
    ST[(e >> 2) * 16 + 12 + (e & 3)] = 0;
  }
#pragma unroll
  for (int i = 0; i < 6; ++i) {  // 12 ci x 128 col
    const int e = i * 256 + t;   // 0..1535
    const int ci = e >> 7, col = e & 127;
    const float v = img[(((size_t)(b * 12 + ci)) << 14) + row * 128 + col];
    ST[col * 16 + ci] = f2bf(v);
  }
  __syncthreads();
  us4* dst = (us4*)(imgT + (((size_t)(b * 128 + row)) << 11));
#pragma unroll
  for (int i = 0; i < 2; ++i) {
    const int q = i * 256 + t;  // 0..511 us4 chunks
    dst[q] = *(const us4*)&ST[q * 4];
  }
}

// ---------------- kw: w2 f32 [co][64][3][3] -> bf16 A-fragments, K-order k=32ks+g*8+j,
// k -> (rc = k>>6, ci = k&63), src = w2[co*576 + ci*9 + rc]. idx=((cot*18+ks)*64+lane)*8+j
__global__ __launch_bounds__(256) void kw_prep(const float* __restrict__ w2,
                                               u16* __restrict__ Aw) {
  const int idx = blockIdx.x * 256 + threadIdx.x;  // 0..73727
  const int j = idx & 7;
  const int lane = (idx >> 3) & 63;
  const int t3 = idx >> 9;
  const int ks = t3 % 18, cot = t3 / 18;
  const int m = lane & 15, g = lane >> 4;
  const int co = cot * 16 + m;
  const int k = ks * 32 + g * 8 + j;
  const int rc = k >> 6, ci = k & 63;
  Aw[idx] = f2bf(w2[co * 576 + ci * 9 + rc]);
}

// ---------------- kw1: w1 f32 [co][12][3][3] -> bf16 A-frags, K padded 108->160.
// k=32ks+g*8+j -> (rc=k>>4, cip=k&15); pad (rc>=9 || cip>=12) -> 0.
__global__ __launch_bounds__(256) void kw1_prep(const float* __restrict__ w1,
                                                u16* __restrict__ Aw1) {
  const int idx = blockIdx.x * 256 + threadIdx.x;  // 0..10239
  const int j = idx & 7;
  const int lane = (idx >> 3) & 63;
  const int t3 = idx >> 9;           // cot*5 + ks
  const int ks = t3 % 5, cot = t3 / 5;
  const int m = lane & 15, g = lane >> 4;
  const int co = cot * 16 + m;
  const int k = ks * 32 + g * 8 + j;
  const int rc = k >> 4, cip = k & 15;
  const float v = (rc < 9 && cip < 12) ? w1[co * 108 + cip * 9 + rc] : 0.f;
  Aw1[idx] = f2bf(v);
}

// ---------------- k1: conv1 (MFMA) + bias + relu + pool -> pooledT bf16 [b][ph][pw][co]
// block: (h2 = pooled row, b). Stages img rows 2h2-1..2h2+2 as [4][128 col][16 cip].
// wave wv: co-tiles {2(wv&1), +1} x cols [ (wv>>1)*64, +64 ) x conv rows {2h2, 2h2+1}.
__global__ __launch_bounds__(256) void k1_mfma(const u16* __restrict__ imgT,
                                               const u16* __restrict__ Aw1,
                                               const float* __restrict__ b1,
                                               u16* __restrict__ pooledT) {
  __shared__ alignas(16) u16 SIMG[8192];     // 16 KB
  __shared__ alignas(16) u16 PT[64 * 68];    // pooled [pw][co], pad-68 stride
  const int h2 = blockIdx.x, b = blockIdx.y;
  const int t = threadIdx.x, wv = t >> 6, l = t & 63;

#pragma unroll
  for (int i = 0; i < 4; ++i) {  // stage 4 rows x 4KB
    const int q = i * 256 + t;   // 16B chunk 0..1023
    const int sr = q >> 8, off = q & 255;
    const int irow = 2 * h2 - 1 + sr;
    short8 v = {0, 0, 0, 0, 0, 0, 0, 0};
    if ((unsigned)irow < 128u)
      v = *(const short8*)(imgT + (((size_t)(b * 128 + irow)) << 11) + off * 8);
    *(short8*)(SIMG + q * 8) = v;
  }
  __syncthreads();

  const int m16 = l & 15, g = l >> 4;
  const int colhalf = wv >> 1, cotbase = (wv & 1) * 2;
  f32x4 acc[2][8];
#pragma unroll
  for (int ct = 0; ct < 2; ++ct)
#pragma unroll
    for (int pt = 0; pt < 8; ++pt) acc[ct][pt] = (f32x4){0.f, 0.f, 0.f, 0.f};

  const u16* awb = Aw1 + (size_t)l * 8;
  const int cipb = (g & 1) * 16;  // byte offset of cip0 within 32B col-slot

#pragma unroll
  for (int ks = 0; ks < 5; ++ks) {
    short8 a0 = *(const short8*)(awb + (cotbase * 5 + ks) * 512);
    short8 a1 = *(const short8*)(awb + ((cotbase + 1) * 5 + ks) * 512);
    const bool pad = (ks == 4) && (g >= 2);  // k in [144,160): zero slots
    int rc = pad ? 0 : (2 * ks + (g >> 1));  // 0..8
    const int rr = (rc * 11) >> 5;           // rc/3
    const int cc = rc - rr * 3;              // rc%3
#pragma unroll
    for (int pt = 0; pt < 8; ++pt) {
      const int r01 = pt >> 2, ct2 = pt & 3;
      const int icol = colhalf * 64 + ct2 * 16 + m16 - 1 + cc;  // -1..128
      const bool ok = ((unsigned)icol < 128u) && !pad;
      const int ic = ok ? icol : 0;
      const int sr = r01 + rr;  // 0..3 (pad forces rr=0)
      short8 bv = *(const short8*)((const char*)SIMG + sr * 4096 + ic * 32 + cipb);
      if (!ok) bv = (short8){0, 0, 0, 0, 0, 0, 0, 0};
      acc[0][pt] = __builtin_amdgcn_mfma_f32_16x16x32_bf16(a0, bv, acc[0][pt], 0, 0, 0);
      acc[1][pt] = __builtin_amdgcn_mfma_f32_16x16x32_bf16(a1, bv, acc[1][pt], 0, 0, 0);
    }
  }

  // relu + 2x2 pool (rows in-lane, col pairs via shfl_xor) -> PT[pw][co]
#pragma unroll
  for (int ct = 0; ct < 2; ++ct) {
    const int cot = cotbase + ct;
#pragma unroll
    for (int r = 0; r < 4; ++r) {
      const int co = cot * 16 + g * 4 + r;
      const float bias = b1[co];
#pragma unroll
      for (int ct2 = 0; ct2 < 4; ++ct2) {
        float v0 = fmaxf(acc[ct][ct2][r] + bias, 0.f);
        float v1 = fmaxf(acc[ct][4 + ct2][r] + bias, 0.f);
        float vv = fmaxf(v0, v1);
        vv = fmaxf(vv, __shfl_xor(vv, 1, 64));
        if (!(m16 & 1)) {
          const int pw = colhalf * 32 + ct2 * 8 + (m16 >> 1);
          PT[pw * 68 + co] = f2bf(vv);
        }
      }
    }
  }
  __syncthreads();
  u16* dst = pooledT + (((size_t)(b * 64 + h2)) << 12);
#pragma unroll
  for (int i = 0; i < 4; ++i) {
    const int e = (i * 256 + t) * 4;
    const int pw = e >> 6, co = e & 63;
    *(us4*)(dst + e) = *(const us4*)&PT[pw * 68 + co];
  }
}

// ---------------- k2: conv2 (MFMA) + bias + relu + PE -> x2 f32 [b][co][h][w]
// block: (h, b). Stages pooledT rows h-1..h+1 as [3][64 col][64 ci], XOR-swizzled.
// wave wv: co-tiles {2wv, 2wv+1} x all 64 cols (4 pos-tiles). K = 576 = 18 ksteps.
__global__ __launch_bounds__(256) void k2_mfma(const u16* __restrict__ pooledT,
                                               const u16* __restrict__ Aw,
                                               const float* __restrict__ b2,
                                               const float* __restrict__ dw,
                                               const float* __restrict__ db,
                                               float* __restrict__ x2) {
  __shared__ alignas(16) short8 SIN8[1536];  // 24 KB
  char* SB = (char*)SIN8;
  const int h = blockIdx.x, b = blockIdx.y;
  const int t = threadIdx.x, wv = t >> 6, l = t & 63;

#pragma unroll
  for (int i = 0; i < 6; ++i) {  // 24 chunks x 1KB
    const int chunk = i * 4 + wv;
    const int row = chunk >> 3;
    const int hin = h - 1 + row;
    short8 v = {0, 0, 0, 0, 0, 0, 0, 0};
    if ((unsigned)hin < 64u)
      v = *(const short8*)(pooledT + (((size_t)(b * 64 + hin)) << 12) +
                           ((chunk & 7) << 9) + l * 8);
    const int lin = chunk * 1024 + l * 16;
    *(short8*)(SB + (lin ^ (((lin >> 7) & 7) << 4))) = v;  // T2 XOR swizzle
  }
  __syncthreads();

  const int m16 = l & 15, g = l >> 4;
  const int kbyte = g * 16;
  f32x4 acc[2][4];
#pragma unroll
  for (int ct = 0; ct < 2; ++ct)
#pragma unroll
    for (int n = 0; n < 4; ++n) acc[ct][n] = (f32x4){0.f, 0.f, 0.f, 0.f};

  const u16* aw0 = Aw + (size_t)wv * 36 * 512 + l * 8;  // cot = 2wv

#pragma unroll
  for (int ks = 0; ks < 18; ++ks) {
    const int rc = ks >> 1, r = rc / 3, c = rc % 3;  // compile-time
    const int koff = r * 8192 + (ks & 1) * 64 + kbyte;
    short8 a0 = *(const short8*)(aw0 + ks * 512);
    short8 a1 = *(const short8*)(aw0 + (18 + ks) * 512);
    const int d = m16 + c - 1;  // -1..16
#pragma unroll
    for (int n = 0; n < 4; ++n) {
      const int icol = n * 16 + d;
      const bool ok = (unsigned)icol < 64u;
      const int ic = ok ? icol : (icol < 0 ? 0 : 63);
      int addr = koff + ic * 128;
      addr ^= (ic & 7) << 4;  // matching read-side swizzle
      short8 bv = *(const short8*)(SB + addr);
      if (!ok) bv = (short8){0, 0, 0, 0, 0, 0, 0, 0};
      acc[0][n] = __builtin_amdgcn_mfma_f32_16x16x32_bf16(a0, bv, acc[0][n], 0, 0, 0);
      acc[1][n] = __builtin_amdgcn_mfma_f32_16x16x32_bf16(a1, bv, acc[1][n], 0, 0, 0);
    }
  }

  // epilogue: relu(acc + b2) + pe ; pe = gy*(W0-W2) + gx*(W1-W3) + W2+W3+db
  const float inv63 = 1.f / 63.f;
  const float gy = (float)h * inv63;
#pragma unroll
  for (int ct = 0; ct < 2; ++ct) {
    const int cot = wv * 2 + ct;
#pragma unroll
    for (int r = 0; r < 4; ++r) {
      const int co = cot * 16 + g * 4 + r;
      const float bias = b2[co];
      const float W0 = dw[co * 4 + 0], W1 = dw[co * 4 + 1];
      const float W2 = dw[co * 4 + 2], W3 = dw[co * 4 + 3];
      const float pe0 = gy * (W0 - W2) + W2 + W3 + db[co];
      const float s13 = W1 - W3;
      float* orow = x2 + (((size_t)(b * 128 + co)) << 12) + h * 64;
#pragma unroll
      for (int n = 0; n < 4; ++n) {
        const int w = n * 16 + m16;
        orow[w] = fmaxf(acc[ct][n][r] + bias, 0.f) + pe0 + (float)w * inv63 * s13;
      }
    }
  }
}

// ---------------- k3: out[b,o,c] = max over pos of x2[b,c,pos] * r[b,o,pos] ---
__global__ __launch_bounds__(256) void k3_roi(const float* __restrict__ x2,
                                              const unsigned* __restrict__ rmask,
                                              float* __restrict__ out) {
  __shared__ float red[4][32];
  const int c = blockIdx.x, b = blockIdx.y;
  const int t = threadIdx.x;
  const float* plane = x2 + (size_t)(b * 128 + c) * 4096;
  const unsigned* mb = rmask + b * 4096;

  float m[32];
#pragma unroll
  for (int o = 0; o < 32; ++o) m[o] = -3.4e38f;

  for (int k = 0; k < 16; ++k) {
    const int pos = k * 256 + t;
    const float xv = plane[pos];
    const unsigned mk = mb[pos];
#pragma unroll
    for (int o = 0; o < 32; ++o) {
      m[o] = fmaxf(m[o], ((mk >> o) & 1u) ? xv : 0.f);
    }
  }

#pragma unroll
  for (int o = 0; o < 32; ++o) {
#pragma unroll
    for (int s = 32; s >= 1; s >>= 1) {
      m[o] = fmaxf(m[o], __shfl_xor(m[o], s, 64));
    }
  }
  const int wave = t >> 6, lane = t & 63;
  if (lane == 0) {
#pragma unroll
    for (int o = 0; o < 32; ++o) red[wave][o] = m[o];
  }
  __syncthreads();
  if (t < 32) {
    float v = fmaxf(fmaxf(red[0][t], red[1][t]), fmaxf(red[2][t], red[3][t]));
    out[((size_t)b * 32 + t) * 128 + c] = v;
  }
}

}  // namespace

extern "C" void kernel_launch(void* const* d_in, const int* in_sizes, int n_in,
                              void* d_out, int out_size, void* d_ws, size_t ws_size,
                              hipStream_t stream) {
  const float* images = (const float*)d_in[0];
  const unsigned* rois = (const unsigned*)d_in[1];
  const float* w1 = (const float*)d_in[2];
  const float* b1 = (const float*)d_in[3];
  const float* w2 = (const float*)d_in[4];
  const float* b2 = (const float*)d_in[5];
  const float* dw = (const float*)d_in[6];
  const float* db = (const float*)d_in[7];
  float* out = (float*)d_out;

  char* ws = (char*)d_ws;
  // rmask 256KB @0 ; pooledT 8MB @0x40000 ; Aw2 144KB @0x840000 ; Aw1 20KB @0x864000
  // imgT 8MB @0x900000 (dead after k1) ; x2 32MB @0x900000 (overlaps imgT; written in k2)
  unsigned* rmask = (unsigned*)(ws);
  u16* pooledT = (u16*)(ws + 0x40000);
  u16* Aw2 = (u16*)(ws + 0x840000);
  u16* Aw1 = (u16*)(ws + 0x864000);
  u16* imgT = (u16*)(ws + 0x900000);
  float* x2 = (float*)(ws + 0x900000);

  hipLaunchKernelGGL(k0_rmask, dim3(256), dim3(256), 0, stream, rois, rmask);
  hipLaunchKernelGGL(k0b_imgT, dim3(128, 16), dim3(256), 0, stream, images, imgT);
  hipLaunchKernelGGL(kw_prep, dim3(288), dim3(256), 0, stream, w2, Aw2);
  hipLaunchKernelGGL(kw1_prep, dim3(40), dim3(256), 0, stream, w1, Aw1);
  hipLaunchKernelGGL(k1_mfma, dim3(64, 16), dim3(256), 0, stream, imgT, Aw1, b1, pooledT);
  hipLaunchKernelGGL(k2_mfma, dim3(64, 16), dim3(256), 0, stream, pooledT, Aw2, b2, dw, db, x2);
  hipLaunchKernelGGL(k3_roi, dim3(128, 16), dim3(256), 0, stream, x2, rmask, out);
}